// Round 8
// baseline (1676.179 us; speedup 1.0000x reference)
//
#include <hip/hip_runtime.h>

// ContextTokenModel — round 8: round-6 scalar pipeline with FP32 OUTPUT.
// Root cause of rounds 3-7: d_out is a float32 buffer (beacon experiment in
// round 7 proved the comparator never saw a bf16 write at element 0); all
// prior rounds stored bf16 ushorts, so the comparator read junk pairs.
// embed (token emb + masked max over type emb) -> 2-layer biGRU.
// B=8192, T=21, D_in=160, H=32. Output fp32 [B,21,64] (fw | bw).

typedef unsigned short ushort_t;

#define U_TOKEMB  0
#define U_TYPEMB  640000
#define U_HOLE    800000
#define U_GKFW0   800160
#define U_GBFW0   812448
#define U_CKFW0   812512
#define U_CBFW0   818656
#define U_GKBW0   818688
#define U_GBBW0   830976
#define U_CKBW0   831040
#define U_CBBW0   837184
#define U_GKFW1   837216
#define U_GBFW1   843360
#define U_CKFW1   843424
#define U_CBFW1   846496
#define U_GKBW1   846528
#define U_GBBW1   852672
#define U_CKBW1   852736
#define U_CBBW1   855808

#define MB_OFF    3500032u      // mask bitmasks: ushort [2][81920]
#define Y0_OFF    4194304u      // y0 bf16 [21][8192][64]; ends < 25 MiB

__device__ __forceinline__ float bf2f(unsigned int u) {
  union { unsigned int i; float f; } v; v.i = u << 16; return v.f;
}
__device__ __forceinline__ unsigned short f2bf(float f) {
  unsigned int u = __float_as_uint(f);
  u += 0x7fffu + ((u >> 16) & 1u);
  return (unsigned short)(u >> 16);
}
__device__ __forceinline__ float sgm(float x) {
  x = fminf(fmaxf(x, -30.f), 30.f);
  return 1.f / (1.f + __expf(-x));
}
__device__ __forceinline__ float tnh(float x) {
  x = fminf(fmaxf(x, -15.f), 15.f);
  float e = __expf(2.f * x);
  return (e - 1.f) / (e + 1.f);
}

// ---------------------------------------------------------------------------
// k0: probes. flags[0]: 1 = float inputs fp32-encoded (else bf16 ushorts).
// flags[1]: mask encoding: 0=4-byte words (int32/fp32, nonzero test), 1=bytes.
// flags[2]: 1 if types/mask slots swapped.
// ---------------------------------------------------------------------------
__global__ void k0_detect(const ushort_t* __restrict__ probe_f,
                          const unsigned* __restrict__ probe_m,
                          const unsigned* __restrict__ probe_t,
                          int* __restrict__ flags) {
  const int lane = threadIdx.x;  // 64
  int cnt = 0;
#pragma unroll
  for (int i = 0; i < 4; ++i) {
    unsigned e = ((unsigned)probe_f[lane + i * 64] >> 7) & 0xffu;
    if (e == 0u || (e >= 112u && e <= 134u)) cnt++;
  }
#pragma unroll
  for (int off = 32; off > 0; off >>= 1) cnt += __shfl_down(cnt, off, 64);

  const unsigned v = probe_m[lane];
  const unsigned long long bytelike =
      __ballot((v > 1u) && (v != 0x3F800000u) && ((v & 0xFEFEFEFEu) == 0u));
  const unsigned tv = probe_t[lane];
  const unsigned long long tlooksTypes =
      __ballot(!(tv == 0u || tv == 1u || tv == 0x3F800000u));
  if (lane == 0) {
    flags[0] = (cnt < 205) ? 1 : 0;
    flags[1] = bytelike ? 1 : 0;
    flags[2] = tlooksTypes ? 0 : 1;
  }
}

struct Cvt19 { const void* src[19]; int len[19]; int dst[19]; };

__global__ void kcvt(Cvt19 a, float* __restrict__ W, const int* __restrict__ flags) {
  const int fp32 = flags[0];
  int gid = blockIdx.x * blockDim.x + threadIdx.x;
#pragma unroll 1
  for (int s = 0; s < 19; ++s) {
    if (gid < a.len[s]) {
      W[a.dst[s] + gid] = fp32 ? ((const float*)a.src[s])[gid]
                               : bf2f((unsigned)((const ushort_t*)a.src[s])[gid]);
      return;
    }
    gid -= a.len[s];
  }
}

__global__ void kmask(const void* __restrict__ slot_tb, const void* __restrict__ slot_mb,
                      const void* __restrict__ slot_ta, const void* __restrict__ slot_ma,
                      ushort_t* __restrict__ mbits, const int* __restrict__ flags) {
  const int id = blockIdx.x * blockDim.x + threadIdx.x;
  if (id >= 163840) return;
  const int side = (id >= 81920) ? 1 : 0;
  const int idx = id - side * 81920;
  const int sw = flags[2];
  const void* src = side ? (sw ? slot_ta : slot_ma)
                         : (sw ? slot_tb : slot_mb);
  unsigned bits = 0;
  if (flags[1] == 1) {
    const unsigned char* p = (const unsigned char*)src;
#pragma unroll
    for (int nt = 0; nt < 10; ++nt) bits |= (p[idx * 10 + nt] ? 1u : 0u) << nt;
  } else {
    const unsigned* p = (const unsigned*)src;
#pragma unroll
    for (int nt = 0; nt < 10; ++nt) bits |= (p[idx * 10 + nt] ? 1u : 0u) << nt;
  }
  mbits[side * 81920 + idx] = (ushort_t)bits;
}

// ---------------------------------------------------------------------------
// kgru0: layer-0 recurrence + fused embedding. One wave per (b, dir).
// Writes y0 bf16 [t][8192][64] (fw|bw).
// ---------------------------------------------------------------------------
__global__ __launch_bounds__(256) void kgru0(
    const int* __restrict__ tok_b, const void* __restrict__ slot_tb,
    const void* __restrict__ slot_mb,
    const int* __restrict__ tok_a, const void* __restrict__ slot_ta,
    const void* __restrict__ slot_ma,
    const float* __restrict__ W, const ushort_t* __restrict__ mbits,
    ushort_t* __restrict__ yout, const int* __restrict__ flags) {
  __shared__ float wgL[192 * 64];
  __shared__ float gbL[64], cbL[32];
  __shared__ float xl[4][192];
  __shared__ float hl[4][32], rhl[4][32], ul[4][32];

  const int wv = threadIdx.x >> 6;
  const int lane = threadIdx.x & 63;
  const int dir = blockIdx.x & 1;
  const int b = (blockIdx.x >> 1) * 4 + wv;
  const int sw = flags[2];
  const int* typ_b = (const int*)(sw ? slot_mb : slot_tb);
  const int* typ_a = (const int*)(sw ? slot_ma : slot_ta);

  const float* gk = W + (dir ? U_GKBW0 : U_GKFW0);
  const float* gb = W + (dir ? U_GBBW0 : U_GBFW0);
  const float* ck = W + (dir ? U_CKBW0 : U_CKFW0);
  const float* cb = W + (dir ? U_CBBW0 : U_CBFW0);

  for (int i = threadIdx.x; i < 192 * 64; i += 256) wgL[i] = gk[i];
  if (threadIdx.x < 64) gbL[threadIdx.x] = gb[threadIdx.x];
  else if (threadIdx.x < 96) cbL[threadIdx.x - 64] = cb[threadIdx.x - 64];
  if (lane < 32) hl[wv][lane] = 0.f;
  __syncthreads();

  for (int s = 0; s < 21; ++s) {
    const int t = dir ? 20 - s : s;

    if (t == 10) {
      for (int k = lane; k < 160; k += 64) xl[wv][k] = W[U_HOLE + k];
    } else {
      const int ts = (t < 10) ? t : t - 11;
      const int side = (t < 10) ? 0 : 1;
      const int* tks = side ? tok_a : tok_b;
      const int* tys = side ? typ_a : typ_b;
      const int tok = tks[b * 10 + ts];
      for (int k = lane; k < 128; k += 64) xl[wv][k] = W[U_TOKEMB + tok * 128 + k];
      if (lane < 32) {
        const unsigned bm = (unsigned)mbits[side * 81920 + b * 10 + ts];
        const int base = (b * 10 + ts) * 10;
        float mx = -1e30f;
        for (int nt = 0; nt < 10; ++nt) {
          const int ty = tys[base + nt];
          const float pen = ((bm >> nt) & 1u) ? 0.f : -1000.f;
          mx = fmaxf(mx, W[U_TYPEMB + ty * 32 + lane] + pen);
        }
        xl[wv][128 + lane] = mx;
      }
    }
    __syncthreads();

    float acc = gbL[lane];
    for (int k = 0; k < 160; ++k) acc += xl[wv][k] * wgL[k * 64 + lane];
#pragma unroll
    for (int k = 0; k < 32; ++k) acc += hl[wv][k] * wgL[(160 + k) * 64 + lane];
    const float g = sgm(acc);
    if (lane < 32) rhl[wv][lane] = g * hl[wv][lane];
    else           ul[wv][lane - 32] = g;
    __syncthreads();

    if (lane < 32) {
      float a2 = cbL[lane];
      for (int k = 0; k < 160; ++k) a2 += xl[wv][k] * ck[k * 32 + lane];
#pragma unroll
      for (int k = 0; k < 32; ++k) a2 += rhl[wv][k] * ck[(160 + k) * 32 + lane];
      const float c = tnh(a2);
      const float u = ul[wv][lane];
      const float hn = u * hl[wv][lane] + (1.f - u) * c;
      hl[wv][lane] = hn;
      yout[((size_t)t * 8192 + b) * 64 + dir * 32 + lane] = f2bf(hn);
    }
    __syncthreads();
  }
}

// ---------------------------------------------------------------------------
// kgru1: layer-1 recurrence. Writes FP32 output [b][21][64] (fw|bw).
// ---------------------------------------------------------------------------
__global__ __launch_bounds__(256) void kgru1(
    const ushort_t* __restrict__ xin, const float* __restrict__ W,
    float* __restrict__ out) {
  __shared__ float wgL[96 * 64];
  __shared__ float gbL[64], cbL[32];
  __shared__ float xl[4][64];
  __shared__ float hl[4][32], rhl[4][32], ul[4][32];

  const int wv = threadIdx.x >> 6;
  const int lane = threadIdx.x & 63;
  const int dir = blockIdx.x & 1;
  const int b = (blockIdx.x >> 1) * 4 + wv;

  const float* gk = W + (dir ? U_GKBW1 : U_GKFW1);
  const float* gb = W + (dir ? U_GBBW1 : U_GBFW1);
  const float* ck = W + (dir ? U_CKBW1 : U_CKFW1);
  const float* cb = W + (dir ? U_CBBW1 : U_CBFW1);

  for (int i = threadIdx.x; i < 96 * 64; i += 256) wgL[i] = gk[i];
  if (threadIdx.x < 64) gbL[threadIdx.x] = gb[threadIdx.x];
  else if (threadIdx.x < 96) cbL[threadIdx.x - 64] = cb[threadIdx.x - 64];
  if (lane < 32) hl[wv][lane] = 0.f;
  __syncthreads();

  for (int s = 0; s < 21; ++s) {
    const int t = dir ? 20 - s : s;
    const ushort_t* xr = xin + ((size_t)t * 8192 + b) * 64;
    xl[wv][lane] = bf2f((unsigned)xr[lane]);
    __syncthreads();

    float acc = gbL[lane];
#pragma unroll
    for (int k = 0; k < 64; ++k) acc += xl[wv][k] * wgL[k * 64 + lane];
#pragma unroll
    for (int k = 0; k < 32; ++k) acc += hl[wv][k] * wgL[(64 + k) * 64 + lane];
    const float g = sgm(acc);
    if (lane < 32) rhl[wv][lane] = g * hl[wv][lane];
    else           ul[wv][lane - 32] = g;
    __syncthreads();

    if (lane < 32) {
      float a2 = cbL[lane];
#pragma unroll
      for (int k = 0; k < 64; ++k) a2 += xl[wv][k] * ck[k * 32 + lane];
#pragma unroll
      for (int k = 0; k < 32; ++k) a2 += rhl[wv][k] * ck[(64 + k) * 32 + lane];
      const float c = tnh(a2);
      const float u = ul[wv][lane];
      const float hn = u * hl[wv][lane] + (1.f - u) * c;
      hl[wv][lane] = hn;
      out[((size_t)b * 21 + t) * 64 + dir * 32 + lane] = hn;   // FP32 store
    }
    __syncthreads();
  }
}

extern "C" void kernel_launch(void* const* d_in, const int* in_sizes, int n_in,
                              void* d_out, int out_size, void* d_ws, size_t ws_size,
                              hipStream_t stream)
{
  const int* tok_b = (const int*)d_in[0];
  const void* slot_tb = d_in[1];
  const void* slot_mb = d_in[2];
  const int* tok_a = (const int*)d_in[3];
  const void* slot_ta = d_in[4];
  const void* slot_ma = d_in[5];

  int* flags = (int*)d_ws;
  float* W = (float*)((char*)d_ws + 64);
  ushort_t* mbits = (ushort_t*)((char*)d_ws + MB_OFF);
  ushort_t* y0 = (ushort_t*)((char*)d_ws + Y0_OFF);

  k0_detect<<<dim3(1), dim3(64), 0, stream>>>(
      (const ushort_t*)d_in[6], (const unsigned*)slot_mb, (const unsigned*)slot_tb,
      flags);

  static const int slen[19] = {640000, 160000, 160,
                               12288, 64, 6144, 32, 12288, 64, 6144, 32,
                               6144, 64, 3072, 32, 6144, 64, 3072, 32};
  static const int sdst[19] = {U_TOKEMB, U_TYPEMB, U_HOLE,
                               U_GKFW0, U_GBFW0, U_CKFW0, U_CBFW0,
                               U_GKBW0, U_GBBW0, U_CKBW0, U_CBBW0,
                               U_GKFW1, U_GBFW1, U_CKFW1, U_CBFW1,
                               U_GKBW1, U_GBBW1, U_CKBW1, U_CBBW1};
  Cvt19 a;
  int tot = 0;
  for (int i = 0; i < 19; ++i) {
    a.src[i] = d_in[6 + i]; a.len[i] = slen[i]; a.dst[i] = sdst[i]; tot += slen[i];
  }
  kcvt<<<dim3((tot + 255) / 256), dim3(256), 0, stream>>>(a, W, flags);

  kmask<<<dim3(640), dim3(256), 0, stream>>>(
      slot_tb, slot_mb, slot_ta, slot_ma, mbits, flags);

  kgru0<<<dim3(4096), dim3(256), 0, stream>>>(
      tok_b, slot_tb, slot_mb, tok_a, slot_ta, slot_ma, W, mbits, y0, flags);

  kgru1<<<dim3(4096), dim3(256), 0, stream>>>(y0, W, (float*)d_out);
}

// Round 9
// 245.806 us; speedup vs baseline: 6.8191x; 6.8191x over previous
//
#include <hip/hip_runtime.h>

// ContextTokenModel — round 9: MFMA pipeline (validated in r3 via bit-identical
// outputs vs the scalar anchor) + fp32 output (r8's root-cause fix).
// Layer 0: FUSED embed + x-projection + recurrence, fp32 MFMA accumulators.
// Layer 1: r3's k3_layer1 with fp32 stores.
// B=8192, T=21, D_in=160, H=32. Output fp32 [B,21,64] (fw|bw).

typedef __attribute__((ext_vector_type(8))) short short8;
typedef __attribute__((ext_vector_type(8))) __bf16 bf16x8;
typedef __attribute__((ext_vector_type(4))) float f32x4;
typedef unsigned short ushort_t;

// ---- bf16 cvt region (ushort offsets from ws+64) ----
#define U_TOKEMB  0             // 5000*128
#define U_TYPEMB  640000        // 5000*32
#define U_HOLE    800000        // 160
#define U_GKFW0   800160        // 192*64
#define U_GBFW0   812448        // 64
#define U_CKFW0   812512        // 192*32
#define U_CBFW0   818656        // 32
#define U_GKBW0   818688
#define U_GBBW0   830976
#define U_CKBW0   831040
#define U_CBBW0   837184
#define U_GKFW1   837216        // 96*64
#define U_GBFW1   843360
#define U_CKFW1   843424        // 96*32
#define U_CBFW1   846496
#define U_GKBW1   846528
#define U_GBBW1   852672
#define U_CKBW1   852736
#define U_CBBW1   855808
// cvt ends at 64 + 855840*2 = 1,711,744 B

#define MB_OFF    (2u << 20)    // mask bitmasks: ushort [2][81920]
#define Y0A_OFF   (4u << 20)    // y0a bf16 A-frags: uint4 [21*512][2][64] = 22,020,096 B

__device__ __forceinline__ float bf2f(unsigned int u) {
  union { unsigned int i; float f; } v; v.i = u << 16; return v.f;
}
__device__ __forceinline__ unsigned short f2bf(float f) {
  unsigned int u = __float_as_uint(f);
  u += 0x7fffu + ((u >> 16) & 1u);
  return (unsigned short)(u >> 16);
}
__device__ __forceinline__ f32x4 mfma16(short8 a, short8 b, f32x4 c) {
  return __builtin_amdgcn_mfma_f32_16x16x32_bf16(
      __builtin_bit_cast(bf16x8, a), __builtin_bit_cast(bf16x8, b), c, 0, 0, 0);
}
__device__ __forceinline__ float sgm(float x) {
  x = fminf(fmaxf(x, -30.f), 30.f);
  return 1.f / (1.f + __expf(-x));
}
__device__ __forceinline__ float tnh(float x) {
  x = fminf(fmaxf(x, -15.f), 15.f);
  float e = __expf(2.f * x);
  return (e - 1.f) / (e + 1.f);
}

// ---------------------------------------------------------------------------
// k0 probes (validated in r8). flags[0]=fp32 floats; flags[1]=byte masks;
// flags[2]=types/mask slots swapped.
// ---------------------------------------------------------------------------
__global__ void k0_detect(const ushort_t* __restrict__ probe_f,
                          const unsigned* __restrict__ probe_m,
                          const unsigned* __restrict__ probe_t,
                          int* __restrict__ flags) {
  const int lane = threadIdx.x;  // 64
  int cnt = 0;
#pragma unroll
  for (int i = 0; i < 4; ++i) {
    unsigned e = ((unsigned)probe_f[lane + i * 64] >> 7) & 0xffu;
    if (e == 0u || (e >= 112u && e <= 134u)) cnt++;
  }
#pragma unroll
  for (int off = 32; off > 0; off >>= 1) cnt += __shfl_down(cnt, off, 64);
  const unsigned v = probe_m[lane];
  const unsigned long long bytelike =
      __ballot((v > 1u) && (v != 0x3F800000u) && ((v & 0xFEFEFEFEu) == 0u));
  const unsigned tv = probe_t[lane];
  const unsigned long long tlooksTypes =
      __ballot(!(tv == 0u || tv == 1u || tv == 0x3F800000u));
  if (lane == 0) {
    flags[0] = (cnt < 205) ? 1 : 0;
    flags[1] = bytelike ? 1 : 0;
    flags[2] = tlooksTypes ? 0 : 1;
  }
}

// ---------------------------------------------------------------------------
// kcvt: normalize all 19 float inputs to bf16 cvt region.
// ---------------------------------------------------------------------------
struct Cvt19 { const void* src[19]; int len[19]; int dst[19]; };

__global__ void kcvt(Cvt19 a, ushort_t* __restrict__ cvt, const int* __restrict__ flags) {
  const int fp32 = flags[0];
  int gid = blockIdx.x * blockDim.x + threadIdx.x;
#pragma unroll 1
  for (int s = 0; s < 19; ++s) {
    if (gid < a.len[s]) {
      cvt[a.dst[s] + gid] = fp32 ? f2bf(((const float*)a.src[s])[gid])
                                 : ((const ushort_t*)a.src[s])[gid];
      return;
    }
    gid -= a.len[s];
  }
}

__global__ void kmask(const void* __restrict__ slot_tb, const void* __restrict__ slot_mb,
                      const void* __restrict__ slot_ta, const void* __restrict__ slot_ma,
                      ushort_t* __restrict__ mbits, const int* __restrict__ flags) {
  const int id = blockIdx.x * blockDim.x + threadIdx.x;
  if (id >= 163840) return;
  const int side = (id >= 81920) ? 1 : 0;
  const int idx = id - side * 81920;
  const int sw = flags[2];
  const void* src = side ? (sw ? slot_ta : slot_ma) : (sw ? slot_tb : slot_mb);
  unsigned bits = 0;
  if (flags[1] == 1) {
    const unsigned char* p = (const unsigned char*)src;
#pragma unroll
    for (int nt = 0; nt < 10; ++nt) bits |= (p[idx * 10 + nt] ? 1u : 0u) << nt;
  } else {
    const unsigned* p = (const unsigned*)src;
#pragma unroll
    for (int nt = 0; nt < 10; ++nt) bits |= (p[idx * 10 + nt] ? 1u : 0u) << nt;
  }
  mbits[side * 81920 + idx] = (ushort_t)bits;
}

// ---------------------------------------------------------------------------
// x-gather: fill A-frags af[0..4] for timestep t, batch rows btile*16+(lane&15).
// af[kt][j] = x[b][kt*32 + (lane>>4)*8 + j] as bf16 bits.
// ---------------------------------------------------------------------------
__device__ __forceinline__ void gatherX(
    int t, int btile, int nl, int q,
    const int* __restrict__ tok_b, const int* __restrict__ typ_b,
    const int* __restrict__ tok_a, const int* __restrict__ typ_a,
    const ushort_t* __restrict__ cvt, const ushort_t* __restrict__ mbits,
    short8 af[5]) {
  const int b = btile * 16 + nl;
  if (t == 10) {
#pragma unroll
    for (int kt = 0; kt < 5; ++kt)
      af[kt] = __builtin_bit_cast(short8,
          *reinterpret_cast<const uint4*>(cvt + U_HOLE + kt * 32 + q * 8));
    return;
  }
  const int ts = (t < 10) ? t : t - 11;
  const int side = (t < 10) ? 0 : 1;
  const int* tks = side ? tok_a : tok_b;
  const int* tys = side ? typ_a : typ_b;
  const int tok = tks[b * 10 + ts];
#pragma unroll
  for (int kt = 0; kt < 4; ++kt)
    af[kt] = __builtin_bit_cast(short8,
        *reinterpret_cast<const uint4*>(cvt + U_TOKEMB + (size_t)tok * 128 + kt * 32 + q * 8));
  const unsigned bm = (unsigned)mbits[side * 81920 + b * 10 + ts];
  float mx[8];
#pragma unroll
  for (int j = 0; j < 8; ++j) mx[j] = -1e30f;
  const int base = (b * 10 + ts) * 10;
  for (int nt = 0; nt < 10; ++nt) {
    const int ty = tys[base + nt];
    const float pen = ((bm >> nt) & 1u) ? 0.f : -1000.f;
    uint4 e = *reinterpret_cast<const uint4*>(cvt + U_TYPEMB + (size_t)ty * 32 + q * 8);
    const unsigned w[4] = {e.x, e.y, e.z, e.w};
#pragma unroll
    for (int j2 = 0; j2 < 4; ++j2) {
      mx[2 * j2]     = fmaxf(mx[2 * j2],     bf2f(w[j2] & 0xffffu) + pen);
      mx[2 * j2 + 1] = fmaxf(mx[2 * j2 + 1], bf2f(w[j2] >> 16) + pen);
    }
  }
  short8 v;
#pragma unroll
  for (int j = 0; j < 8; ++j) v[j] = (short)f2bf(mx[j]);
  af[4] = v;
}

// ---------------------------------------------------------------------------
// kfused0: layer-0 embed + projection + recurrence. 1024 wave-jobs
// (512 btiles x 2 dirs), 16 batch rows per wave. Gates/candidate computed as
// fp32 MFMA accumulators: sigma(x@Wxg + h@Whg + bg), tanh(x@Wxc + rh@Whc + bc).
// Writes y0a bf16 A-frags uint4 [(t*512+btile)*2+dir][lane].
// ---------------------------------------------------------------------------
__global__ __launch_bounds__(256) void kfused0(
    const int* __restrict__ tok_b, const void* __restrict__ slot_tb,
    const int* __restrict__ tok_a, const void* __restrict__ slot_ta,
    const void* __restrict__ slot_mb, const void* __restrict__ slot_ma,
    const ushort_t* __restrict__ cvt, const ushort_t* __restrict__ mbits,
    uint4* __restrict__ y0a, const int* __restrict__ flags) {
  __shared__ __align__(16) ushort_t hbuf[4][2][16 * 40];
  const int wv = threadIdx.x >> 6;
  const int lane = threadIdx.x & 63;
  const int q = lane >> 4, nl = lane & 15;
  const int job = blockIdx.x * 4 + wv;
  const int dir = job & 1, btile = job >> 1;
  const int sw = flags[2];
  const int* typ_b = (const int*)(sw ? slot_mb : slot_tb);
  const int* typ_a = (const int*)(sw ? slot_ma : slot_ta);

  const ushort_t* gk = cvt + (dir ? U_GKBW0 : U_GKFW0);  // [192][64]
  const ushort_t* ck = cvt + (dir ? U_CKBW0 : U_CKFW0);  // [192][32]
  const ushort_t* gb = cvt + (dir ? U_GBBW0 : U_GBFW0);
  const ushort_t* cb = cvt + (dir ? U_CBBW0 : U_CBFW0);

  // B-fragments: Wx gates (5 kt x 4 tn), Wx cand (5 x 2), Wh gates (4), Wh cand (2)
  short8 wg[5][4], wc[5][2], wgh[4], wch[2];
#pragma unroll
  for (int kt = 0; kt < 5; ++kt) {
#pragma unroll
    for (int tn = 0; tn < 4; ++tn) {
      short8 v;
#pragma unroll
      for (int j = 0; j < 8; ++j) v[j] = (short)gk[(kt * 32 + q * 8 + j) * 64 + tn * 16 + nl];
      wg[kt][tn] = v;
    }
#pragma unroll
    for (int tn = 0; tn < 2; ++tn) {
      short8 v;
#pragma unroll
      for (int j = 0; j < 8; ++j) v[j] = (short)ck[(kt * 32 + q * 8 + j) * 32 + tn * 16 + nl];
      wc[kt][tn] = v;
    }
  }
#pragma unroll
  for (int tn = 0; tn < 4; ++tn) {
    short8 v;
#pragma unroll
    for (int j = 0; j < 8; ++j) v[j] = (short)gk[(160 + q * 8 + j) * 64 + tn * 16 + nl];
    wgh[tn] = v;
  }
#pragma unroll
  for (int tn = 0; tn < 2; ++tn) {
    short8 v;
#pragma unroll
    for (int j = 0; j < 8; ++j) v[j] = (short)ck[(160 + q * 8 + j) * 32 + tn * 16 + nl];
    wch[tn] = v;
  }
  float gb4[4], cb4[2];
#pragma unroll
  for (int tn = 0; tn < 4; ++tn) gb4[tn] = bf2f((unsigned)gb[tn * 16 + nl]);
#pragma unroll
  for (int tn = 0; tn < 2; ++tn) cb4[tn] = bf2f((unsigned)cb[tn * 16 + nl]);

  f32x4 hc0 = {0.f, 0.f, 0.f, 0.f}, hc1 = {0.f, 0.f, 0.f, 0.f};
  short8 hA = {0, 0, 0, 0, 0, 0, 0, 0};
  ushort_t* hb0 = hbuf[wv][0];
  ushort_t* hb1 = hbuf[wv][1];

  short8 afc[5], afn[5];
  gatherX(dir ? 20 : 0, btile, nl, q, tok_b, typ_b, tok_a, typ_a, cvt, mbits, afc);

  for (int s = 0; s < 21; ++s) {
    const int t = dir ? 20 - s : s;
    if (s < 20)
      gatherX(dir ? t - 1 : t + 1, btile, nl, q, tok_b, typ_b, tok_a, typ_a, cvt, mbits, afn);

    // gates
    f32x4 ru[4];
#pragma unroll
    for (int tn = 0; tn < 4; ++tn) {
      f32x4 acc = {gb4[tn], gb4[tn], gb4[tn], gb4[tn]};
#pragma unroll
      for (int kt = 0; kt < 5; ++kt) acc = mfma16(afc[kt], wg[kt][tn], acc);
      acc = mfma16(hA, wgh[tn], acc);
      ru[tn] = acc;
    }
#pragma unroll
    for (int tn = 0; tn < 4; ++tn)
#pragma unroll
      for (int r = 0; r < 4; ++r) ru[tn][r] = sgm(ru[tn][r]);

    // r*h -> A-layout via LDS
#pragma unroll
    for (int r = 0; r < 4; ++r) {
      hb0[(q * 4 + r) * 40 + nl]      = f2bf(ru[0][r] * hc0[r]);
      hb0[(q * 4 + r) * 40 + 16 + nl] = f2bf(ru[1][r] * hc1[r]);
    }
    __syncthreads();
    short8 rhA = *reinterpret_cast<const short8*>(hb0 + nl * 40 + q * 8);

    // candidate
    f32x4 cc0 = {cb4[0], cb4[0], cb4[0], cb4[0]};
    f32x4 cc1 = {cb4[1], cb4[1], cb4[1], cb4[1]};
#pragma unroll
    for (int kt = 0; kt < 5; ++kt) {
      cc0 = mfma16(afc[kt], wc[kt][0], cc0);
      cc1 = mfma16(afc[kt], wc[kt][1], cc1);
    }
    cc0 = mfma16(rhA, wch[0], cc0);
    cc1 = mfma16(rhA, wch[1], cc1);
#pragma unroll
    for (int r = 0; r < 4; ++r) {
      const float c0 = tnh(cc0[r]), c1 = tnh(cc1[r]);
      const float u0 = ru[2][r], u1 = ru[3][r];
      hc0[r] = u0 * hc0[r] + (1.f - u0) * c0;
      hc1[r] = u1 * hc1[r] + (1.f - u1) * c1;
    }

    // h' -> A-layout (next step's operand + y0 output)
#pragma unroll
    for (int r = 0; r < 4; ++r) {
      hb1[(q * 4 + r) * 40 + nl]      = f2bf(hc0[r]);
      hb1[(q * 4 + r) * 40 + 16 + nl] = f2bf(hc1[r]);
    }
    __syncthreads();
    hA = *reinterpret_cast<const short8*>(hb1 + nl * 40 + q * 8);
    y0a[((size_t)(t * 512 + btile) * 2 + dir) * 64 + lane] = __builtin_bit_cast(uint4, hA);

    if (s < 20) {
#pragma unroll
      for (int kt = 0; kt < 5; ++kt) afc[kt] = afn[kt];
    }
  }
}

// ---------------------------------------------------------------------------
// k3b: layer-1 recurrence (r3-validated); FP32 output [b][21][64].
// ---------------------------------------------------------------------------
__global__ __launch_bounds__(256) void k3b(
    const ushort_t* __restrict__ cvt, const uint4* __restrict__ y0a,
    float* __restrict__ out) {
  __shared__ __align__(16) ushort_t hbuf[4][2][16 * 40];
  const int wv = threadIdx.x >> 6;
  const int lane = threadIdx.x & 63;
  const int q = lane >> 4, nl = lane & 15;
  const int job = blockIdx.x * 4 + wv;
  const int dir = job & 1, btile = job >> 1;
  const ushort_t* gk = cvt + (dir ? U_GKBW1 : U_GKFW1);
  const ushort_t* ck = cvt + (dir ? U_CKBW1 : U_CKFW1);
  const ushort_t* gb = cvt + (dir ? U_GBBW1 : U_GBFW1);
  const ushort_t* cb = cvt + (dir ? U_CBBW1 : U_CBFW1);

  short8 wg[3][4], wc[3][2];
#pragma unroll
  for (int kt = 0; kt < 3; ++kt) {
#pragma unroll
    for (int tn = 0; tn < 4; ++tn) {
      short8 v;
#pragma unroll
      for (int j = 0; j < 8; ++j) v[j] = (short)gk[(kt * 32 + q * 8 + j) * 64 + tn * 16 + nl];
      wg[kt][tn] = v;
    }
#pragma unroll
    for (int tn = 0; tn < 2; ++tn) {
      short8 v;
#pragma unroll
      for (int j = 0; j < 8; ++j) v[j] = (short)ck[(kt * 32 + q * 8 + j) * 32 + tn * 16 + nl];
      wc[kt][tn] = v;
    }
  }
  float gb4[4], cb4[2];
#pragma unroll
  for (int tn = 0; tn < 4; ++tn) gb4[tn] = bf2f((unsigned)gb[tn * 16 + nl]);
#pragma unroll
  for (int tn = 0; tn < 2; ++tn) cb4[tn] = bf2f((unsigned)cb[tn * 16 + nl]);

  f32x4 hc0 = {0.f, 0.f, 0.f, 0.f}, hc1 = {0.f, 0.f, 0.f, 0.f};
  short8 hA = {0, 0, 0, 0, 0, 0, 0, 0};
  ushort_t* hb0 = hbuf[wv][0];
  ushort_t* hb1 = hbuf[wv][1];

  short8 ya0, ya1, yn0, yn1;
  {
    const int t0 = dir ? 20 : 0;
    ya0 = __builtin_bit_cast(short8, y0a[((size_t)(t0 * 512 + btile) * 2 + 0) * 64 + lane]);
    ya1 = __builtin_bit_cast(short8, y0a[((size_t)(t0 * 512 + btile) * 2 + 1) * 64 + lane]);
  }

  for (int s = 0; s < 21; ++s) {
    const int t = dir ? 20 - s : s;
    if (s < 20) {
      const int t2 = dir ? t - 1 : t + 1;
      yn0 = __builtin_bit_cast(short8, y0a[((size_t)(t2 * 512 + btile) * 2 + 0) * 64 + lane]);
      yn1 = __builtin_bit_cast(short8, y0a[((size_t)(t2 * 512 + btile) * 2 + 1) * 64 + lane]);
    }

    f32x4 ru[4];
#pragma unroll
    for (int tn = 0; tn < 4; ++tn) {
      f32x4 acc = {gb4[tn], gb4[tn], gb4[tn], gb4[tn]};
      acc = mfma16(ya0, wg[0][tn], acc);
      acc = mfma16(ya1, wg[1][tn], acc);
      acc = mfma16(hA,  wg[2][tn], acc);
      ru[tn] = acc;
    }
#pragma unroll
    for (int tn = 0; tn < 4; ++tn)
#pragma unroll
      for (int r = 0; r < 4; ++r) ru[tn][r] = sgm(ru[tn][r]);

#pragma unroll
    for (int r = 0; r < 4; ++r) {
      hb0[(q * 4 + r) * 40 + nl]      = f2bf(ru[0][r] * hc0[r]);
      hb0[(q * 4 + r) * 40 + 16 + nl] = f2bf(ru[1][r] * hc1[r]);
    }
    __syncthreads();
    short8 rhA = *reinterpret_cast<const short8*>(hb0 + nl * 40 + q * 8);

    f32x4 cc0 = {cb4[0], cb4[0], cb4[0], cb4[0]};
    cc0 = mfma16(ya0, wc[0][0], cc0);
    cc0 = mfma16(ya1, wc[1][0], cc0);
    cc0 = mfma16(rhA, wc[2][0], cc0);
    f32x4 cc1 = {cb4[1], cb4[1], cb4[1], cb4[1]};
    cc1 = mfma16(ya0, wc[0][1], cc1);
    cc1 = mfma16(ya1, wc[1][1], cc1);
    cc1 = mfma16(rhA, wc[2][1], cc1);

#pragma unroll
    for (int r = 0; r < 4; ++r) {
      const float c0 = tnh(cc0[r]), c1 = tnh(cc1[r]);
      const float u0 = ru[2][r], u1 = ru[3][r];
      hc0[r] = u0 * hc0[r] + (1.f - u0) * c0;
      hc1[r] = u1 * hc1[r] + (1.f - u1) * c1;
    }

#pragma unroll
    for (int r = 0; r < 4; ++r) {
      hb1[(q * 4 + r) * 40 + nl]      = f2bf(hc0[r]);
      hb1[(q * 4 + r) * 40 + 16 + nl] = f2bf(hc1[r]);
    }
    __syncthreads();
    hA = *reinterpret_cast<const short8*>(hb1 + nl * 40 + q * 8);

    // FP32 output: lane holds h'[m=q*4+r][ch nl and 16+nl] for this dir
#pragma unroll
    for (int r = 0; r < 4; ++r) {
      const size_t o = ((size_t)(btile * 16 + q * 4 + r) * 21 + t) * 64 + dir * 32 + nl;
      out[o]      = hc0[r];
      out[o + 16] = hc1[r];
    }

    if (s < 20) { ya0 = yn0; ya1 = yn1; }
  }
}

// ---------------------------------------------------------------------------
extern "C" void kernel_launch(void* const* d_in, const int* in_sizes, int n_in,
                              void* d_out, int out_size, void* d_ws, size_t ws_size,
                              hipStream_t stream)
{
  const int* tok_b = (const int*)d_in[0];
  const void* slot_tb = d_in[1];
  const void* slot_mb = d_in[2];
  const int* tok_a = (const int*)d_in[3];
  const void* slot_ta = d_in[4];
  const void* slot_ma = d_in[5];

  int* flags = (int*)d_ws;
  ushort_t* cvt = (ushort_t*)((char*)d_ws + 64);
  ushort_t* mbits = (ushort_t*)((char*)d_ws + MB_OFF);
  uint4* y0a = (uint4*)((char*)d_ws + Y0A_OFF);

  k0_detect<<<dim3(1), dim3(64), 0, stream>>>(
      (const ushort_t*)d_in[6], (const unsigned*)slot_mb, (const unsigned*)slot_tb,
      flags);

  static const int slen[19] = {640000, 160000, 160,
                               12288, 64, 6144, 32, 12288, 64, 6144, 32,
                               6144, 64, 3072, 32, 6144, 64, 3072, 32};
  static const int sdst[19] = {U_TOKEMB, U_TYPEMB, U_HOLE,
                               U_GKFW0, U_GBFW0, U_CKFW0, U_CBFW0,
                               U_GKBW0, U_GBBW0, U_CKBW0, U_CBBW0,
                               U_GKFW1, U_GBFW1, U_CKFW1, U_CBFW1,
                               U_GKBW1, U_GBBW1, U_CKBW1, U_CBBW1};
  Cvt19 a;
  int tot = 0;
  for (int i = 0; i < 19; ++i) {
    a.src[i] = d_in[6 + i]; a.len[i] = slen[i]; a.dst[i] = sdst[i]; tot += slen[i];
  }
  kcvt<<<dim3((tot + 255) / 256), dim3(256), 0, stream>>>(a, cvt, flags);

  kmask<<<dim3(640), dim3(256), 0, stream>>>(
      slot_tb, slot_mb, slot_ta, slot_ma, mbits, flags);

  kfused0<<<dim3(256), dim3(256), 0, stream>>>(
      tok_b, slot_tb, tok_a, slot_ta, slot_mb, slot_ma, cvt, mbits, y0a, flags);

  k3b<<<dim3(256), dim3(256), 0, stream>>>(cvt, y0a, (float*)d_out);
}